// Round 1
// baseline (1175.104 us; speedup 1.0000x reference)
//
#include <hip/hip_runtime.h>
#include <math.h>

#define NATOM 300000
#define NBOND 310000
#define NANGLE 550000
#define NTORSION 800000
#define N14 800000
#define NNB 3000000

// output segment offsets (concat order from reference)
#define OFF_KATOM   0
#define OFF_EQATOM  300000
#define OFF_BOND0   600000
#define OFF_BOND1   910000
#define OFF_ANG0    1220000
#define OFF_ANG1    1770000
#define OFF_TOR0    2320000
#define OFF_TOR1    3120000
#define OFF_S14     3920000
#define OFF_E14     4720000
#define OFF_SNB     5520000
#define OFF_ENB     8520000

__device__ __forceinline__ float fast_tanh(float z) {
    float az = fabsf(z);
    float e  = __expf(-2.0f * az);             // v_exp_f32 path
    float t  = __fdividef(1.0f - e, 1.0f + e); // v_rcp_f32 fast divide
    return copysignf(t, z);
}

// MODE 0: atom (x = h[row])
// MODE 1: bond (x = h[i0]+h[i1], idx pitch 2)
// MODE 2: angle (x = h[c]+h[s0]+h[s1])
// MODE 3: torsion (x = h[t2]+h[t3], idx pitch 4, elems 2,3)
template<int MODE>
__global__ __launch_bounds__(256)
void mlp_k(const float* __restrict__ h,
           const int* __restrict__ ia, const int* __restrict__ ib,
           const float* __restrict__ W1, const float* __restrict__ b1,
           const float* __restrict__ W2, const float* __restrict__ b2,
           float* __restrict__ o0p, float* __restrict__ o1p, int n)
{
    __shared__ float sW1[128 * 32];
    __shared__ float sB1[32];
    __shared__ float sW2[64];
    __shared__ float sB2[2];

    const int tid = threadIdx.x;
    {   // cooperative stage of weights into LDS (float4, coalesced)
        const float4* W1v = (const float4*)W1;
        float4* sW1v = (float4*)sW1;
        #pragma unroll
        for (int i = 0; i < 4; ++i) sW1v[tid + 256 * i] = W1v[tid + 256 * i];
        if (tid < 32) sB1[tid] = b1[tid];
        if (tid < 64) sW2[tid] = W2[tid];
        if (tid < 2)  sB2[tid] = b2[tid];
    }
    __syncthreads();

    const int row = blockIdx.x * 256 + tid;
    if (row >= n) return;

    const float4* x0;
    const float4* x1 = nullptr;
    const float4* x2 = nullptr;
    if constexpr (MODE == 0) {
        x0 = (const float4*)(h + (size_t)row * 128);
    } else if constexpr (MODE == 1) {
        int2 p = ((const int2*)ia)[row];
        x0 = (const float4*)(h + (size_t)p.x * 128);
        x1 = (const float4*)(h + (size_t)p.y * 128);
    } else if constexpr (MODE == 2) {
        int c  = ia[row];
        int2 p = ((const int2*)ib)[row];
        x0 = (const float4*)(h + (size_t)c * 128);
        x1 = (const float4*)(h + (size_t)p.x * 128);
        x2 = (const float4*)(h + (size_t)p.y * 128);
    } else {
        int4 q = ((const int4*)ia)[row];
        x0 = (const float4*)(h + (size_t)q.z * 128);
        x1 = (const float4*)(h + (size_t)q.w * 128);
    }

    float acc[32];
    #pragma unroll
    for (int j = 0; j < 32; ++j) acc[j] = sB1[j];

    #pragma unroll 2
    for (int kk = 0; kk < 32; ++kk) {
        float4 a = x0[kk];
        if constexpr (MODE == 1 || MODE == 3) {
            float4 bq = x1[kk];
            a.x += bq.x; a.y += bq.y; a.z += bq.z; a.w += bq.w;
        } else if constexpr (MODE == 2) {
            float4 bq = x1[kk];
            float4 cq = x2[kk];
            a.x += bq.x + cq.x; a.y += bq.y + cq.y;
            a.z += bq.z + cq.z; a.w += bq.w + cq.w;
        }
        const float* wr = &sW1[kk * 4 * 32];
        #pragma unroll
        for (int j = 0; j < 32; ++j) acc[j] = fmaf(a.x, wr[j], acc[j]);
        #pragma unroll
        for (int j = 0; j < 32; ++j) acc[j] = fmaf(a.y, wr[32 + j], acc[j]);
        #pragma unroll
        for (int j = 0; j < 32; ++j) acc[j] = fmaf(a.z, wr[64 + j], acc[j]);
        #pragma unroll
        for (int j = 0; j < 32; ++j) acc[j] = fmaf(a.w, wr[96 + j], acc[j]);
    }

    float o0 = sB2[0], o1 = sB2[1];
    #pragma unroll
    for (int j = 0; j < 32; ++j) {
        float t = fast_tanh(acc[j]);
        o0 = fmaf(t, sW2[2 * j], o0);
        o1 = fmaf(t, sW2[2 * j + 1], o1);
    }
    o0p[row] = fabsf(o0);
    o1p[row] = fabsf(o1);
}

__global__ __launch_bounds__(256)
void pair_k(const float* __restrict__ kat, const float* __restrict__ eat,
            const int* __restrict__ idx,
            float* __restrict__ sig, float* __restrict__ eps, int n)
{
    int i = blockIdx.x * 256 + threadIdx.x;
    if (i >= n) return;
    int2 p = ((const int2*)idx)[i];
    float ka = kat[p.x], kb = kat[p.y];
    float ea = eat[p.x], eb = eat[p.y];
    sig[i] = 0.5f * (ka + kb);
    eps[i] = sqrtf(ea * eb);
}

extern "C" void kernel_launch(void* const* d_in, const int* in_sizes, int n_in,
                              void* d_out, int out_size, void* d_ws, size_t ws_size,
                              hipStream_t stream)
{
    const float* h     = (const float*)d_in[0];
    const int*   bond  = (const int*)d_in[1];
    const int*   ang_c = (const int*)d_in[2];
    const int*   ang_s = (const int*)d_in[3];
    const int*   tor   = (const int*)d_in[4];
    const int*   i14   = (const int*)d_in[5];
    const int*   inb   = (const int*)d_in[6];
    const float* W1a   = (const float*)d_in[7];
    const float* b1a   = (const float*)d_in[8];
    const float* W2a   = (const float*)d_in[9];
    const float* b2a   = (const float*)d_in[10];
    const float* W1b   = (const float*)d_in[11];
    const float* b1b   = (const float*)d_in[12];
    const float* W2b   = (const float*)d_in[13];
    const float* b2b   = (const float*)d_in[14];
    float* out = (float*)d_out;

    dim3 B(256);
    mlp_k<0><<<(NATOM    + 255) / 256, B, 0, stream>>>(h, nullptr, nullptr, W1a, b1a, W2a, b2a,
                                                       out + OFF_KATOM, out + OFF_EQATOM, NATOM);
    mlp_k<1><<<(NBOND    + 255) / 256, B, 0, stream>>>(h, bond, nullptr, W1b, b1b, W2b, b2b,
                                                       out + OFF_BOND0, out + OFF_BOND1, NBOND);
    mlp_k<2><<<(NANGLE   + 255) / 256, B, 0, stream>>>(h, ang_c, ang_s, W1b, b1b, W2b, b2b,
                                                       out + OFF_ANG0, out + OFF_ANG1, NANGLE);
    mlp_k<3><<<(NTORSION + 255) / 256, B, 0, stream>>>(h, tor, nullptr, W1b, b1b, W2b, b2b,
                                                       out + OFF_TOR0, out + OFF_TOR1, NTORSION);
    pair_k<<<(N14 + 255) / 256, B, 0, stream>>>(out + OFF_KATOM, out + OFF_EQATOM, i14,
                                                out + OFF_S14, out + OFF_E14, N14);
    pair_k<<<(NNB + 255) / 256, B, 0, stream>>>(out + OFF_KATOM, out + OFF_EQATOM, inb,
                                                out + OFF_SNB, out + OFF_ENB, NNB);
}

// Round 2
// 272.424 us; speedup vs baseline: 4.3135x; 4.3135x over previous
//
#include <hip/hip_runtime.h>
#include <math.h>

#define NATOM 300000
#define NBOND 310000
#define NANGLE 550000
#define NTORSION 800000
#define N14 800000
#define NNB 3000000

// output segment offsets (concat order from reference)
#define OFF_KATOM   0
#define OFF_EQATOM  300000
#define OFF_BOND0   600000
#define OFF_BOND1   910000
#define OFF_ANG0    1220000
#define OFF_ANG1    1770000
#define OFF_TOR0    2320000
#define OFF_TOR1    3120000
#define OFF_S14     3920000
#define OFF_E14     4720000
#define OFF_SNB     5520000
#define OFF_ENB     8520000

// workspace layout
#define ZB_BYTES  ((size_t)NATOM * 32 * sizeof(float))        // 38.4 MB
#define KE_BYTES  ((size_t)NATOM * 2 * sizeof(float))         // 2.4 MB
#define WS_NEED   (ZB_BYTES + KE_BYTES)

__device__ __forceinline__ float fast_tanh(float z) {
    float az = fabsf(z);
    float e  = __expf(-2.0f * az);
    float t  = __fdividef(1.0f - e, 1.0f + e);
    return copysignf(t, z);
}

// ---------------- fast path ----------------

// Fused: atom MLP (W1a) -> k_atom/eq_atom/ke table, plus z_b = h @ W1b (no bias)
__global__ __launch_bounds__(256)
void atom_all_k(const float* __restrict__ h,
                const float* __restrict__ W1a, const float* __restrict__ b1a,
                const float* __restrict__ W2a, const float* __restrict__ b2a,
                const float* __restrict__ W1b,
                float* __restrict__ kout, float* __restrict__ eout,
                float* __restrict__ zb, float2* __restrict__ ke)
{
    __shared__ float sWa[128 * 32];
    __shared__ float sWb[128 * 32];
    const int tid = threadIdx.x;
    {
        const float4* A = (const float4*)W1a;
        const float4* B = (const float4*)W1b;
        float4* a4 = (float4*)sWa;
        float4* b4 = (float4*)sWb;
        #pragma unroll
        for (int i = 0; i < 4; ++i) {
            a4[tid + 256 * i] = A[tid + 256 * i];
            b4[tid + 256 * i] = B[tid + 256 * i];
        }
    }
    __syncthreads();

    const int row = blockIdx.x * 256 + tid;
    if (row >= NATOM) return;

    float acca[32], accb[32];
    #pragma unroll
    for (int j = 0; j < 32; ++j) { acca[j] = b1a[j]; accb[j] = 0.0f; }

    const float4* x4 = (const float4*)(h + (size_t)row * 128);
    for (int kk = 0; kk < 32; ++kk) {
        float4 a = x4[kk];
        const float* wa = &sWa[kk * 128];
        const float* wb = &sWb[kk * 128];
        #pragma unroll
        for (int j = 0; j < 32; ++j) acca[j] = fmaf(a.x, wa[j],      acca[j]);
        #pragma unroll
        for (int j = 0; j < 32; ++j) acca[j] = fmaf(a.y, wa[32 + j], acca[j]);
        #pragma unroll
        for (int j = 0; j < 32; ++j) acca[j] = fmaf(a.z, wa[64 + j], acca[j]);
        #pragma unroll
        for (int j = 0; j < 32; ++j) acca[j] = fmaf(a.w, wa[96 + j], acca[j]);
        #pragma unroll
        for (int j = 0; j < 32; ++j) accb[j] = fmaf(a.x, wb[j],      accb[j]);
        #pragma unroll
        for (int j = 0; j < 32; ++j) accb[j] = fmaf(a.y, wb[32 + j], accb[j]);
        #pragma unroll
        for (int j = 0; j < 32; ++j) accb[j] = fmaf(a.z, wb[64 + j], accb[j]);
        #pragma unroll
        for (int j = 0; j < 32; ++j) accb[j] = fmaf(a.w, wb[96 + j], accb[j]);
    }

    float o0 = b2a[0], o1 = b2a[1];
    #pragma unroll
    for (int j = 0; j < 32; ++j) {
        float t = fast_tanh(acca[j]);
        o0 = fmaf(t, W2a[2 * j],     o0);
        o1 = fmaf(t, W2a[2 * j + 1], o1);
    }
    float kv = fabsf(o0), ev = fabsf(o1);
    kout[row] = kv;
    eout[row] = ev;
    ke[row] = make_float2(kv, ev);

    float4* z4 = (float4*)(zb + (size_t)row * 32);
    #pragma unroll
    for (int c = 0; c < 8; ++c)
        z4[c] = make_float4(accb[4 * c], accb[4 * c + 1], accb[4 * c + 2], accb[4 * c + 3]);
}

// MODE 1: bond (int2 in ia) | MODE 2: angle (ia center, ib int2 sides) | MODE 3: torsion (int4, use .z/.w)
template<int MODE>
__global__ __launch_bounds__(256)
void edge_k(const float* __restrict__ zb,
            const int* __restrict__ ia, const int* __restrict__ ib,
            const float* __restrict__ b1, const float* __restrict__ W2,
            const float* __restrict__ b2,
            float* __restrict__ o0p, float* __restrict__ o1p, int n)
{
    const int row = blockIdx.x * 256 + threadIdx.x;
    if (row >= n) return;

    const float4* p0;
    const float4* p1;
    const float4* p2 = nullptr;
    if constexpr (MODE == 1) {
        int2 p = ((const int2*)ia)[row];
        p0 = (const float4*)(zb + (size_t)p.x * 32);
        p1 = (const float4*)(zb + (size_t)p.y * 32);
    } else if constexpr (MODE == 2) {
        int c  = ia[row];
        int2 s = ((const int2*)ib)[row];
        p0 = (const float4*)(zb + (size_t)c   * 32);
        p1 = (const float4*)(zb + (size_t)s.x * 32);
        p2 = (const float4*)(zb + (size_t)s.y * 32);
    } else {
        int4 q = ((const int4*)ia)[row];
        p0 = (const float4*)(zb + (size_t)q.z * 32);
        p1 = (const float4*)(zb + (size_t)q.w * 32);
    }

    // gather full 128B rows with back-to-back float4 loads (full line use)
    float4 A[8], B[8], C[8];
    #pragma unroll
    for (int c = 0; c < 8; ++c) A[c] = p0[c];
    #pragma unroll
    for (int c = 0; c < 8; ++c) B[c] = p1[c];
    if constexpr (MODE == 2) {
        #pragma unroll
        for (int c = 0; c < 8; ++c) C[c] = p2[c];
    }

    float acc[32];
    #pragma unroll
    for (int c = 0; c < 8; ++c) {
        float4 s;
        s.x = A[c].x + B[c].x; s.y = A[c].y + B[c].y;
        s.z = A[c].z + B[c].z; s.w = A[c].w + B[c].w;
        if constexpr (MODE == 2) {
            s.x += C[c].x; s.y += C[c].y; s.z += C[c].z; s.w += C[c].w;
        }
        acc[4 * c]     = s.x + b1[4 * c];
        acc[4 * c + 1] = s.y + b1[4 * c + 1];
        acc[4 * c + 2] = s.z + b1[4 * c + 2];
        acc[4 * c + 3] = s.w + b1[4 * c + 3];
    }

    float o0 = b2[0], o1 = b2[1];
    #pragma unroll
    for (int j = 0; j < 32; ++j) {
        float t = fast_tanh(acc[j]);
        o0 = fmaf(t, W2[2 * j],     o0);
        o1 = fmaf(t, W2[2 * j + 1], o1);
    }
    o0p[row] = fabsf(o0);
    o1p[row] = fabsf(o1);
}

// 2 pairs per thread; ke interleaved table: one 8B gather per atom
__global__ __launch_bounds__(256)
void pair_ke_k(const float2* __restrict__ ke, const int* __restrict__ idx,
               float* __restrict__ sig, float* __restrict__ eps, int npair)
{
    int i = (blockIdx.x * 256 + threadIdx.x) * 2;
    if (i >= npair) return;
    int4 q = ((const int4*)idx)[i >> 1];
    float2 a0 = ke[q.x], b0 = ke[q.y];
    float2 a1 = ke[q.z], b1v = ke[q.w];
    sig[i]     = 0.5f * (a0.x + b0.x);
    eps[i]     = sqrtf(a0.y * b0.y);
    sig[i + 1] = 0.5f * (a1.x + b1v.x);
    eps[i + 1] = sqrtf(a1.y * b1v.y);
}

// ---------------- fallback path (v1, known-good) ----------------

template<int MODE>
__global__ __launch_bounds__(256)
void mlp_k(const float* __restrict__ h,
           const int* __restrict__ ia, const int* __restrict__ ib,
           const float* __restrict__ W1, const float* __restrict__ b1,
           const float* __restrict__ W2, const float* __restrict__ b2,
           float* __restrict__ o0p, float* __restrict__ o1p, int n)
{
    __shared__ float sW1[128 * 32];
    __shared__ float sB1[32];
    __shared__ float sW2[64];
    __shared__ float sB2[2];

    const int tid = threadIdx.x;
    {
        const float4* W1v = (const float4*)W1;
        float4* sW1v = (float4*)sW1;
        #pragma unroll
        for (int i = 0; i < 4; ++i) sW1v[tid + 256 * i] = W1v[tid + 256 * i];
        if (tid < 32) sB1[tid] = b1[tid];
        if (tid < 64) sW2[tid] = W2[tid];
        if (tid < 2)  sB2[tid] = b2[tid];
    }
    __syncthreads();

    const int row = blockIdx.x * 256 + tid;
    if (row >= n) return;

    const float4* x0;
    const float4* x1 = nullptr;
    const float4* x2 = nullptr;
    if constexpr (MODE == 0) {
        x0 = (const float4*)(h + (size_t)row * 128);
    } else if constexpr (MODE == 1) {
        int2 p = ((const int2*)ia)[row];
        x0 = (const float4*)(h + (size_t)p.x * 128);
        x1 = (const float4*)(h + (size_t)p.y * 128);
    } else if constexpr (MODE == 2) {
        int c  = ia[row];
        int2 p = ((const int2*)ib)[row];
        x0 = (const float4*)(h + (size_t)c * 128);
        x1 = (const float4*)(h + (size_t)p.x * 128);
        x2 = (const float4*)(h + (size_t)p.y * 128);
    } else {
        int4 q = ((const int4*)ia)[row];
        x0 = (const float4*)(h + (size_t)q.z * 128);
        x1 = (const float4*)(h + (size_t)q.w * 128);
    }

    float acc[32];
    #pragma unroll
    for (int j = 0; j < 32; ++j) acc[j] = sB1[j];

    #pragma unroll 2
    for (int kk = 0; kk < 32; ++kk) {
        float4 a = x0[kk];
        if constexpr (MODE == 1 || MODE == 3) {
            float4 bq = x1[kk];
            a.x += bq.x; a.y += bq.y; a.z += bq.z; a.w += bq.w;
        } else if constexpr (MODE == 2) {
            float4 bq = x1[kk];
            float4 cq = x2[kk];
            a.x += bq.x + cq.x; a.y += bq.y + cq.y;
            a.z += bq.z + cq.z; a.w += bq.w + cq.w;
        }
        const float* wr = &sW1[kk * 4 * 32];
        #pragma unroll
        for (int j = 0; j < 32; ++j) acc[j] = fmaf(a.x, wr[j], acc[j]);
        #pragma unroll
        for (int j = 0; j < 32; ++j) acc[j] = fmaf(a.y, wr[32 + j], acc[j]);
        #pragma unroll
        for (int j = 0; j < 32; ++j) acc[j] = fmaf(a.z, wr[64 + j], acc[j]);
        #pragma unroll
        for (int j = 0; j < 32; ++j) acc[j] = fmaf(a.w, wr[96 + j], acc[j]);
    }

    float o0 = sB2[0], o1 = sB2[1];
    #pragma unroll
    for (int j = 0; j < 32; ++j) {
        float t = fast_tanh(acc[j]);
        o0 = fmaf(t, sW2[2 * j], o0);
        o1 = fmaf(t, sW2[2 * j + 1], o1);
    }
    o0p[row] = fabsf(o0);
    o1p[row] = fabsf(o1);
}

__global__ __launch_bounds__(256)
void pair_k(const float* __restrict__ kat, const float* __restrict__ eat,
            const int* __restrict__ idx,
            float* __restrict__ sig, float* __restrict__ eps, int n)
{
    int i = blockIdx.x * 256 + threadIdx.x;
    if (i >= n) return;
    int2 p = ((const int2*)idx)[i];
    float ka = kat[p.x], kb = kat[p.y];
    float ea = eat[p.x], eb = eat[p.y];
    sig[i] = 0.5f * (ka + kb);
    eps[i] = sqrtf(ea * eb);
}

extern "C" void kernel_launch(void* const* d_in, const int* in_sizes, int n_in,
                              void* d_out, int out_size, void* d_ws, size_t ws_size,
                              hipStream_t stream)
{
    const float* h     = (const float*)d_in[0];
    const int*   bond  = (const int*)d_in[1];
    const int*   ang_c = (const int*)d_in[2];
    const int*   ang_s = (const int*)d_in[3];
    const int*   tor   = (const int*)d_in[4];
    const int*   i14   = (const int*)d_in[5];
    const int*   inb   = (const int*)d_in[6];
    const float* W1a   = (const float*)d_in[7];
    const float* b1a   = (const float*)d_in[8];
    const float* W2a   = (const float*)d_in[9];
    const float* b2a   = (const float*)d_in[10];
    const float* W1b   = (const float*)d_in[11];
    const float* b1b   = (const float*)d_in[12];
    const float* W2b   = (const float*)d_in[13];
    const float* b2b   = (const float*)d_in[14];
    float* out = (float*)d_out;

    dim3 B(256);

    if (ws_size >= WS_NEED) {
        float*  zb = (float*)d_ws;
        float2* ke = (float2*)((char*)d_ws + ZB_BYTES);

        atom_all_k<<<(NATOM + 255) / 256, B, 0, stream>>>(
            h, W1a, b1a, W2a, b2a, W1b,
            out + OFF_KATOM, out + OFF_EQATOM, zb, ke);

        edge_k<1><<<(NBOND + 255) / 256, B, 0, stream>>>(
            zb, bond, nullptr, b1b, W2b, b2b, out + OFF_BOND0, out + OFF_BOND1, NBOND);
        edge_k<2><<<(NANGLE + 255) / 256, B, 0, stream>>>(
            zb, ang_c, ang_s, b1b, W2b, b2b, out + OFF_ANG0, out + OFF_ANG1, NANGLE);
        edge_k<3><<<(NTORSION + 255) / 256, B, 0, stream>>>(
            zb, tor, nullptr, b1b, W2b, b2b, out + OFF_TOR0, out + OFF_TOR1, NTORSION);

        pair_ke_k<<<(N14 / 2 + 255) / 256, B, 0, stream>>>(
            ke, i14, out + OFF_S14, out + OFF_E14, N14);
        pair_ke_k<<<(NNB / 2 + 255) / 256, B, 0, stream>>>(
            ke, inb, out + OFF_SNB, out + OFF_ENB, NNB);
    } else {
        mlp_k<0><<<(NATOM    + 255) / 256, B, 0, stream>>>(h, nullptr, nullptr, W1a, b1a, W2a, b2a,
                                                           out + OFF_KATOM, out + OFF_EQATOM, NATOM);
        mlp_k<1><<<(NBOND    + 255) / 256, B, 0, stream>>>(h, bond, nullptr, W1b, b1b, W2b, b2b,
                                                           out + OFF_BOND0, out + OFF_BOND1, NBOND);
        mlp_k<2><<<(NANGLE   + 255) / 256, B, 0, stream>>>(h, ang_c, ang_s, W1b, b1b, W2b, b2b,
                                                           out + OFF_ANG0, out + OFF_ANG1, NANGLE);
        mlp_k<3><<<(NTORSION + 255) / 256, B, 0, stream>>>(h, tor, nullptr, W1b, b1b, W2b, b2b,
                                                           out + OFF_TOR0, out + OFF_TOR1, NTORSION);
        pair_k<<<(N14 + 255) / 256, B, 0, stream>>>(out + OFF_KATOM, out + OFF_EQATOM, i14,
                                                    out + OFF_S14, out + OFF_E14, N14);
        pair_k<<<(NNB + 255) / 256, B, 0, stream>>>(out + OFF_KATOM, out + OFF_EQATOM, inb,
                                                    out + OFF_SNB, out + OFF_ENB, NNB);
    }
}

// Round 3
// 160.780 us; speedup vs baseline: 7.3088x; 1.6944x over previous
//
#include <hip/hip_runtime.h>
#include <math.h>

#define NATOM 300000
#define NBOND 310000
#define NANGLE 550000
#define NTORSION 800000
#define N14 800000
#define NNB 3000000
#define NTILE 18750   // NATOM/16

// output segment offsets (concat order from reference)
#define OFF_KATOM   0
#define OFF_EQATOM  300000
#define OFF_BOND0   600000
#define OFF_BOND1   910000
#define OFF_ANG0    1220000
#define OFF_ANG1    1770000
#define OFF_TOR0    2320000
#define OFF_TOR1    3120000
#define OFF_S14     3920000
#define OFF_E14     4720000
#define OFF_SNB     5520000
#define OFF_ENB     8520000

// workspace layout: [frag table 16KB][zb bf16 19.2MB][ke float2 2.4MB]
#define FRAG_BYTES  16384
#define ZB_BYTES    ((size_t)NATOM * 32 * 2)
#define KE_OFF      (FRAG_BYTES + ZB_BYTES)
#define WS_NEED     (KE_OFF + (size_t)NATOM * 8)

typedef short bf16x8 __attribute__((ext_vector_type(8)));
typedef float f32x4  __attribute__((ext_vector_type(4)));

__device__ __forceinline__ float fast_tanh(float z) {
    float az = fabsf(z);
    float e  = __expf(-2.0f * az);
    float t  = __fdividef(1.0f - e, 1.0f + e);
    return copysignf(t, z);
}

__device__ __forceinline__ unsigned short f2bf(float f) {
    unsigned int u = __float_as_uint(f);
    u = u + 0x7fffu + ((u >> 16) & 1u);   // RTNE
    return (unsigned short)(u >> 16);
}

// ---------------- fast path ----------------

// Pre-pack B fragments of W1a/W1b for mfma_f32_16x16x32_bf16.
// frag index f = ((mat*4 + t)*2 + cb); slot = f*64 + lane.
// lane holds W[k0+i][col], k0 = t*32 + (lane>>4)*8, col = cb*16 + (lane&15), i=0..7.
__global__ __launch_bounds__(256)
void build_frags_k(const float* __restrict__ W1a, const float* __restrict__ W1b,
                   ushort* __restrict__ frag)
{
    int s = blockIdx.x * 256 + threadIdx.x;   // 1024 slots
    if (s >= 1024) return;
    int lane = s & 63;
    int f    = s >> 6;
    int cb   = f & 1;
    int t    = (f >> 1) & 3;
    int mat  = f >> 3;
    const float* W = mat ? W1b : W1a;
    int k0  = t * 32 + (lane >> 4) * 8;
    int col = cb * 16 + (lane & 15);
    ushort* dst = frag + (size_t)s * 8;
    #pragma unroll
    for (int i = 0; i < 8; ++i)
        dst[i] = f2bf(W[(size_t)(k0 + i) * 32 + col]);
}

// One 16-row tile per wave. Computes both matmuls via MFMA:
//   acc[0] = h16x128 @ W1a (-> atom MLP epilogue)
//   acc[1] = h16x128 @ W1b (-> z, stored bf16)
__global__ __launch_bounds__(256)
void atom_mfma_k(const float* __restrict__ h, const bf16x8* __restrict__ frag,
                 const float* __restrict__ b1a, const float* __restrict__ W2a,
                 const float* __restrict__ b2a,
                 float* __restrict__ kout, float* __restrict__ eout,
                 ushort* __restrict__ zb, float2* __restrict__ ke)
{
    const int wid  = threadIdx.x >> 6;
    const int lane = threadIdx.x & 63;
    const int tile = blockIdx.x * 4 + wid;
    if (tile >= NTILE) return;
    const int rowbase = tile * 16;
    const int m = lane & 15;
    const int g = lane >> 4;

    // A fragments: lane holds h[rowbase+m][k = g*8 + t*32 + i], i=0..7
    const float* ap = h + (size_t)(rowbase + m) * 128 + g * 8;
    bf16x8 afr[4];
    #pragma unroll
    for (int t = 0; t < 4; ++t) {
        float4 x0 = *(const float4*)(ap + t * 32);
        float4 x1 = *(const float4*)(ap + t * 32 + 4);
        bf16x8 a;
        a[0] = (short)f2bf(x0.x); a[1] = (short)f2bf(x0.y);
        a[2] = (short)f2bf(x0.z); a[3] = (short)f2bf(x0.w);
        a[4] = (short)f2bf(x1.x); a[5] = (short)f2bf(x1.y);
        a[6] = (short)f2bf(x1.z); a[7] = (short)f2bf(x1.w);
        afr[t] = a;
    }

    f32x4 acc[2][2];
    #pragma unroll
    for (int mat = 0; mat < 2; ++mat) {
        #pragma unroll
        for (int cb = 0; cb < 2; ++cb) {
            f32x4 c = {0.f, 0.f, 0.f, 0.f};
            #pragma unroll
            for (int t = 0; t < 4; ++t) {
                bf16x8 b = frag[(size_t)((((mat << 2) | t) << 1) | cb) * 64 + lane];
                c = __builtin_amdgcn_mfma_f32_16x16x32_bf16(afr[t], b, c, 0, 0, 0);
            }
            acc[mat][cb] = c;
        }
    }

    // z output (mat=1), bf16. D layout: col = m (+16*cb), row = g*4 + r.
    #pragma unroll
    for (int cb = 0; cb < 2; ++cb) {
        int col = cb * 16 + m;
        #pragma unroll
        for (int r = 0; r < 4; ++r) {
            int row = rowbase + g * 4 + r;
            zb[(size_t)row * 32 + col] = f2bf(acc[1][cb][r]);
        }
    }

    // atom MLP epilogue (mat=0): tanh + W2a dot, reduce across 16 lanes
    const int c0 = m, c1 = 16 + m;
    const float w200 = W2a[2 * c0], w201 = W2a[2 * c0 + 1];
    const float w210 = W2a[2 * c1], w211 = W2a[2 * c1 + 1];
    const float bb0 = b1a[c0], bb1 = b1a[c1];
    float o0[4], o1[4];
    #pragma unroll
    for (int r = 0; r < 4; ++r) {
        float t0 = fast_tanh(acc[0][0][r] + bb0);
        float t1 = fast_tanh(acc[0][1][r] + bb1);
        o0[r] = fmaf(t0, w200, t1 * w210);
        o1[r] = fmaf(t0, w201, t1 * w211);
    }
    #pragma unroll
    for (int mask = 1; mask < 16; mask <<= 1) {
        #pragma unroll
        for (int r = 0; r < 4; ++r) {
            o0[r] += __shfl_xor(o0[r], mask, 64);
            o1[r] += __shfl_xor(o1[r], mask, 64);
        }
    }
    if (m == 0) {
        const float B0 = b2a[0], B1 = b2a[1];
        #pragma unroll
        for (int r = 0; r < 4; ++r) {
            int row = rowbase + g * 4 + r;
            float kv = fabsf(o0[r] + B0);
            float ev = fabsf(o1[r] + B1);
            kout[row] = kv;
            eout[row] = ev;
            ke[row]   = make_float2(kv, ev);
        }
    }
}

__device__ __forceinline__ void add_row_bf(float* acc, const uint4* p) {
    #pragma unroll
    for (int c = 0; c < 4; ++c) {
        uint4 u = p[c];
        unsigned int w[4] = {u.x, u.y, u.z, u.w};
        #pragma unroll
        for (int q = 0; q < 4; ++q) {
            acc[c * 8 + q * 2]     += __uint_as_float(w[q] << 16);
            acc[c * 8 + q * 2 + 1] += __uint_as_float(w[q] & 0xffff0000u);
        }
    }
}

// MODE 1: bond (int2) | MODE 2: angle (center + int2 sides) | MODE 3: torsion (int4, .z/.w)
template<int MODE>
__global__ __launch_bounds__(256)
void edge_bf_k(const ushort* __restrict__ zb,
               const int* __restrict__ ia, const int* __restrict__ ib,
               const float* __restrict__ b1, const float* __restrict__ W2,
               const float* __restrict__ b2,
               float* __restrict__ o0p, float* __restrict__ o1p, int n)
{
    const int row = blockIdx.x * 256 + threadIdx.x;
    if (row >= n) return;

    const uint4* p0;
    const uint4* p1;
    const uint4* p2 = nullptr;
    if constexpr (MODE == 1) {
        int2 p = ((const int2*)ia)[row];
        p0 = (const uint4*)(zb + (size_t)p.x * 32);
        p1 = (const uint4*)(zb + (size_t)p.y * 32);
    } else if constexpr (MODE == 2) {
        int c  = ia[row];
        int2 s = ((const int2*)ib)[row];
        p0 = (const uint4*)(zb + (size_t)c   * 32);
        p1 = (const uint4*)(zb + (size_t)s.x * 32);
        p2 = (const uint4*)(zb + (size_t)s.y * 32);
    } else {
        int4 q = ((const int4*)ia)[row];
        p0 = (const uint4*)(zb + (size_t)q.z * 32);
        p1 = (const uint4*)(zb + (size_t)q.w * 32);
    }

    float acc[32];
    #pragma unroll
    for (int j = 0; j < 32; ++j) acc[j] = b1[j];
    add_row_bf(acc, p0);
    add_row_bf(acc, p1);
    if constexpr (MODE == 2) add_row_bf(acc, p2);

    float o0 = b2[0], o1 = b2[1];
    #pragma unroll
    for (int j = 0; j < 32; ++j) {
        float t = fast_tanh(acc[j]);
        o0 = fmaf(t, W2[2 * j],     o0);
        o1 = fmaf(t, W2[2 * j + 1], o1);
    }
    o0p[row] = fabsf(o0);
    o1p[row] = fabsf(o1);
}

// 2 pairs per thread; ke interleaved table: one 8B gather per atom
__global__ __launch_bounds__(256)
void pair_ke_k(const float2* __restrict__ ke, const int* __restrict__ idx,
               float* __restrict__ sig, float* __restrict__ eps, int npair)
{
    int i = (blockIdx.x * 256 + threadIdx.x) * 2;
    if (i >= npair) return;
    int4 q = ((const int4*)idx)[i >> 1];
    float2 a0 = ke[q.x], b0 = ke[q.y];
    float2 a1 = ke[q.z], b1v = ke[q.w];
    sig[i]     = 0.5f * (a0.x + b0.x);
    eps[i]     = sqrtf(a0.y * b0.y);
    sig[i + 1] = 0.5f * (a1.x + b1v.x);
    eps[i + 1] = sqrtf(a1.y * b1v.y);
}

// ---------------- fallback path (v1, known-good) ----------------

template<int MODE>
__global__ __launch_bounds__(256)
void mlp_k(const float* __restrict__ h,
           const int* __restrict__ ia, const int* __restrict__ ib,
           const float* __restrict__ W1, const float* __restrict__ b1,
           const float* __restrict__ W2, const float* __restrict__ b2,
           float* __restrict__ o0p, float* __restrict__ o1p, int n)
{
    __shared__ float sW1[128 * 32];
    __shared__ float sB1[32];
    __shared__ float sW2[64];
    __shared__ float sB2[2];

    const int tid = threadIdx.x;
    {
        const float4* W1v = (const float4*)W1;
        float4* sW1v = (float4*)sW1;
        #pragma unroll
        for (int i = 0; i < 4; ++i) sW1v[tid + 256 * i] = W1v[tid + 256 * i];
        if (tid < 32) sB1[tid] = b1[tid];
        if (tid < 64) sW2[tid] = W2[tid];
        if (tid < 2)  sB2[tid] = b2[tid];
    }
    __syncthreads();

    const int row = blockIdx.x * 256 + tid;
    if (row >= n) return;

    const float4* x0;
    const float4* x1 = nullptr;
    const float4* x2 = nullptr;
    if constexpr (MODE == 0) {
        x0 = (const float4*)(h + (size_t)row * 128);
    } else if constexpr (MODE == 1) {
        int2 p = ((const int2*)ia)[row];
        x0 = (const float4*)(h + (size_t)p.x * 128);
        x1 = (const float4*)(h + (size_t)p.y * 128);
    } else if constexpr (MODE == 2) {
        int c  = ia[row];
        int2 p = ((const int2*)ib)[row];
        x0 = (const float4*)(h + (size_t)c * 128);
        x1 = (const float4*)(h + (size_t)p.x * 128);
        x2 = (const float4*)(h + (size_t)p.y * 128);
    } else {
        int4 q = ((const int4*)ia)[row];
        x0 = (const float4*)(h + (size_t)q.z * 128);
        x1 = (const float4*)(h + (size_t)q.w * 128);
    }

    float acc[32];
    #pragma unroll
    for (int j = 0; j < 32; ++j) acc[j] = sB1[j];

    #pragma unroll 2
    for (int kk = 0; kk < 32; ++kk) {
        float4 a = x0[kk];
        if constexpr (MODE == 1 || MODE == 3) {
            float4 bq = x1[kk];
            a.x += bq.x; a.y += bq.y; a.z += bq.z; a.w += bq.w;
        } else if constexpr (MODE == 2) {
            float4 bq = x1[kk];
            float4 cq = x2[kk];
            a.x += bq.x + cq.x; a.y += bq.y + cq.y;
            a.z += bq.z + cq.z; a.w += bq.w + cq.w;
        }
        const float* wr = &sW1[kk * 4 * 32];
        #pragma unroll
        for (int j = 0; j < 32; ++j) acc[j] = fmaf(a.x, wr[j], acc[j]);
        #pragma unroll
        for (int j = 0; j < 32; ++j) acc[j] = fmaf(a.y, wr[32 + j], acc[j]);
        #pragma unroll
        for (int j = 0; j < 32; ++j) acc[j] = fmaf(a.z, wr[64 + j], acc[j]);
        #pragma unroll
        for (int j = 0; j < 32; ++j) acc[j] = fmaf(a.w, wr[96 + j], acc[j]);
    }

    float o0 = sB2[0], o1 = sB2[1];
    #pragma unroll
    for (int j = 0; j < 32; ++j) {
        float t = fast_tanh(acc[j]);
        o0 = fmaf(t, sW2[2 * j], o0);
        o1 = fmaf(t, sW2[2 * j + 1], o1);
    }
    o0p[row] = fabsf(o0);
    o1p[row] = fabsf(o1);
}

__global__ __launch_bounds__(256)
void pair_k(const float* __restrict__ kat, const float* __restrict__ eat,
            const int* __restrict__ idx,
            float* __restrict__ sig, float* __restrict__ eps, int n)
{
    int i = blockIdx.x * 256 + threadIdx.x;
    if (i >= n) return;
    int2 p = ((const int2*)idx)[i];
    float ka = kat[p.x], kb = kat[p.y];
    float ea = eat[p.x], eb = eat[p.y];
    sig[i] = 0.5f * (ka + kb);
    eps[i] = sqrtf(ea * eb);
}

extern "C" void kernel_launch(void* const* d_in, const int* in_sizes, int n_in,
                              void* d_out, int out_size, void* d_ws, size_t ws_size,
                              hipStream_t stream)
{
    const float* h     = (const float*)d_in[0];
    const int*   bond  = (const int*)d_in[1];
    const int*   ang_c = (const int*)d_in[2];
    const int*   ang_s = (const int*)d_in[3];
    const int*   tor   = (const int*)d_in[4];
    const int*   i14   = (const int*)d_in[5];
    const int*   inb   = (const int*)d_in[6];
    const float* W1a   = (const float*)d_in[7];
    const float* b1a   = (const float*)d_in[8];
    const float* W2a   = (const float*)d_in[9];
    const float* b2a   = (const float*)d_in[10];
    const float* W1b   = (const float*)d_in[11];
    const float* b1b   = (const float*)d_in[12];
    const float* W2b   = (const float*)d_in[13];
    const float* b2b   = (const float*)d_in[14];
    float* out = (float*)d_out;

    dim3 B(256);

    if (ws_size >= WS_NEED) {
        ushort* fragS = (ushort*)d_ws;
        const bf16x8* fragV = (const bf16x8*)d_ws;
        ushort* zb = (ushort*)((char*)d_ws + FRAG_BYTES);
        float2* ke = (float2*)((char*)d_ws + KE_OFF);

        build_frags_k<<<4, B, 0, stream>>>(W1a, W1b, fragS);

        atom_mfma_k<<<(NTILE + 3) / 4, B, 0, stream>>>(
            h, fragV, b1a, W2a, b2a,
            out + OFF_KATOM, out + OFF_EQATOM, zb, ke);

        edge_bf_k<1><<<(NBOND + 255) / 256, B, 0, stream>>>(
            zb, bond, nullptr, b1b, W2b, b2b, out + OFF_BOND0, out + OFF_BOND1, NBOND);
        edge_bf_k<2><<<(NANGLE + 255) / 256, B, 0, stream>>>(
            zb, ang_c, ang_s, b1b, W2b, b2b, out + OFF_ANG0, out + OFF_ANG1, NANGLE);
        edge_bf_k<3><<<(NTORSION + 255) / 256, B, 0, stream>>>(
            zb, tor, nullptr, b1b, W2b, b2b, out + OFF_TOR0, out + OFF_TOR1, NTORSION);

        pair_ke_k<<<(N14 / 2 + 255) / 256, B, 0, stream>>>(
            ke, i14, out + OFF_S14, out + OFF_E14, N14);
        pair_ke_k<<<(NNB / 2 + 255) / 256, B, 0, stream>>>(
            ke, inb, out + OFF_SNB, out + OFF_ENB, NNB);
    } else {
        mlp_k<0><<<(NATOM    + 255) / 256, B, 0, stream>>>(h, nullptr, nullptr, W1a, b1a, W2a, b2a,
                                                           out + OFF_KATOM, out + OFF_EQATOM, NATOM);
        mlp_k<1><<<(NBOND    + 255) / 256, B, 0, stream>>>(h, bond, nullptr, W1b, b1b, W2b, b2b,
                                                           out + OFF_BOND0, out + OFF_BOND1, NBOND);
        mlp_k<2><<<(NANGLE   + 255) / 256, B, 0, stream>>>(h, ang_c, ang_s, W1b, b1b, W2b, b2b,
                                                           out + OFF_ANG0, out + OFF_ANG1, NANGLE);
        mlp_k<3><<<(NTORSION + 255) / 256, B, 0, stream>>>(h, tor, nullptr, W1b, b1b, W2b, b2b,
                                                           out + OFF_TOR0, out + OFF_TOR1, NTORSION);
        pair_k<<<(N14 + 255) / 256, B, 0, stream>>>(out + OFF_KATOM, out + OFF_EQATOM, i14,
                                                    out + OFF_S14, out + OFF_E14, N14);
        pair_k<<<(NNB + 255) / 256, B, 0, stream>>>(out + OFF_KATOM, out + OFF_EQATOM, inb,
                                                    out + OFF_SNB, out + OFF_ENB, NNB);
    }
}

// Round 6
// 142.432 us; speedup vs baseline: 8.2503x; 1.1288x over previous
//
#include <hip/hip_runtime.h>
#include <math.h>

#define NATOM 300000
#define NBOND 310000
#define NANGLE 550000
#define NTORSION 800000
#define N14 800000
#define NNB 3000000
#define NTILE 18750   // NATOM/16

// output segment offsets (concat order from reference)
#define OFF_KATOM   0
#define OFF_EQATOM  300000
#define OFF_BOND0   600000
#define OFF_BOND1   910000
#define OFF_ANG0    1220000
#define OFF_ANG1    1770000
#define OFF_TOR0    2320000
#define OFF_TOR1    3120000
#define OFF_S14     3920000
#define OFF_E14     4720000
#define OFF_SNB     5520000
#define OFF_ENB     8520000

// tail kernel block ranges
#define NB_TOR   3125   // 800000/256 exact
#define NB_ANG   2149   // ceil(550000/256)
#define NB_BOND  1211   // ceil(310000/256)
#define NB_14    1563   // ceil(400000/256), 2 pairs/thread
#define NB_NB    5860   // ceil(1500000/256), 2 pairs/thread
#define NB_TAIL  (NB_TOR + NB_ANG + NB_BOND + NB_14 + NB_NB)

// workspace: [frag table 16KB][zb bf16 19.2MB][ke float2 2.4MB]
#define FRAG_BYTES  16384
#define ZB_BYTES    ((size_t)NATOM * 32 * 2)
#define KE_OFF      (FRAG_BYTES + ZB_BYTES)
#define WS_NEED     (KE_OFF + (size_t)NATOM * 8)

typedef short bf16x8 __attribute__((ext_vector_type(8)));
typedef float f32x4  __attribute__((ext_vector_type(4)));

__device__ __forceinline__ float fast_tanh(float z) {
    float az = fabsf(z);
    float e  = __expf(-2.0f * az);
    float t  = __fdividef(1.0f - e, 1.0f + e);
    return copysignf(t, z);
}

__device__ __forceinline__ unsigned short f2bf(float f) {
    unsigned int u = __float_as_uint(f);
    u = u + 0x7fffu + ((u >> 16) & 1u);   // RTNE
    return (unsigned short)(u >> 16);
}

// ---------------- fast path ----------------

// Pre-pack B fragments of W1a/W1b for mfma_f32_16x16x32_bf16 (r3 verbatim).
__global__ __launch_bounds__(256)
void build_frags_k(const float* __restrict__ W1a, const float* __restrict__ W1b,
                   ushort* __restrict__ frag)
{
    int s = blockIdx.x * 256 + threadIdx.x;   // 1024 slots
    if (s >= 1024) return;
    int lane = s & 63;
    int f    = s >> 6;
    int cb   = f & 1;
    int t    = (f >> 1) & 3;
    int mat  = f >> 3;
    const float* W = mat ? W1b : W1a;
    int k0  = t * 32 + (lane >> 4) * 8;
    int col = cb * 16 + (lane & 15);
    ushort* dst = frag + (size_t)s * 8;
    #pragma unroll
    for (int i = 0; i < 8; ++i)
        dst[i] = f2bf(W[(size_t)(k0 + i) * 32 + col]);
}

// r3 verbatim: one 16-row tile per wave, 4 waves/block, direct z stores.
__global__ __launch_bounds__(256)
void atom_mfma_k(const float* __restrict__ h, const bf16x8* __restrict__ frag,
                 const float* __restrict__ b1a, const float* __restrict__ W2a,
                 const float* __restrict__ b2a,
                 float* __restrict__ kout, float* __restrict__ eout,
                 ushort* __restrict__ zb, float2* __restrict__ ke)
{
    const int wid  = threadIdx.x >> 6;
    const int lane = threadIdx.x & 63;
    const int tile = blockIdx.x * 4 + wid;
    if (tile >= NTILE) return;
    const int rowbase = tile * 16;
    const int m = lane & 15;
    const int g = lane >> 4;

    const float* ap = h + (size_t)(rowbase + m) * 128 + g * 8;
    bf16x8 afr[4];
    #pragma unroll
    for (int t = 0; t < 4; ++t) {
        float4 x0 = *(const float4*)(ap + t * 32);
        float4 x1 = *(const float4*)(ap + t * 32 + 4);
        bf16x8 a;
        a[0] = (short)f2bf(x0.x); a[1] = (short)f2bf(x0.y);
        a[2] = (short)f2bf(x0.z); a[3] = (short)f2bf(x0.w);
        a[4] = (short)f2bf(x1.x); a[5] = (short)f2bf(x1.y);
        a[6] = (short)f2bf(x1.z); a[7] = (short)f2bf(x1.w);
        afr[t] = a;
    }

    f32x4 acc[2][2];
    #pragma unroll
    for (int mat = 0; mat < 2; ++mat) {
        #pragma unroll
        for (int cb = 0; cb < 2; ++cb) {
            f32x4 c = {0.f, 0.f, 0.f, 0.f};
            #pragma unroll
            for (int t = 0; t < 4; ++t) {
                bf16x8 b = frag[(size_t)((((mat << 2) | t) << 1) | cb) * 64 + lane];
                c = __builtin_amdgcn_mfma_f32_16x16x32_bf16(afr[t], b, c, 0, 0, 0);
            }
            acc[mat][cb] = c;
        }
    }

    // z output (mat=1), bf16, direct scattered stores (r3 verbatim)
    #pragma unroll
    for (int cb = 0; cb < 2; ++cb) {
        int col = cb * 16 + m;
        #pragma unroll
        for (int r = 0; r < 4; ++r) {
            int row = rowbase + g * 4 + r;
            zb[(size_t)row * 32 + col] = f2bf(acc[1][cb][r]);
        }
    }

    // atom MLP epilogue (mat=0)
    const int c0 = m, c1 = 16 + m;
    const float w200 = W2a[2 * c0], w201 = W2a[2 * c0 + 1];
    const float w210 = W2a[2 * c1], w211 = W2a[2 * c1 + 1];
    const float bb0 = b1a[c0], bb1 = b1a[c1];
    float o0[4], o1[4];
    #pragma unroll
    for (int r = 0; r < 4; ++r) {
        float t0 = fast_tanh(acc[0][0][r] + bb0);
        float t1 = fast_tanh(acc[0][1][r] + bb1);
        o0[r] = fmaf(t0, w200, t1 * w210);
        o1[r] = fmaf(t0, w201, t1 * w211);
    }
    #pragma unroll
    for (int mask = 1; mask < 16; mask <<= 1) {
        #pragma unroll
        for (int r = 0; r < 4; ++r) {
            o0[r] += __shfl_xor(o0[r], mask, 64);
            o1[r] += __shfl_xor(o1[r], mask, 64);
        }
    }
    if (m == 0) {
        const float B0 = b2a[0], B1 = b2a[1];
        #pragma unroll
        for (int r = 0; r < 4; ++r) {
            int row = rowbase + g * 4 + r;
            float kv = fabsf(o0[r] + B0);
            float ev = fabsf(o1[r] + B1);
            kout[row] = kv;
            eout[row] = ev;
            ke[row]   = make_float2(kv, ev);
        }
    }
}

__device__ __forceinline__ void add_row_bf(float* acc, const uint4* p) {
    #pragma unroll
    for (int c = 0; c < 4; ++c) {
        uint4 u = p[c];
        unsigned int w[4] = {u.x, u.y, u.z, u.w};
        #pragma unroll
        for (int q = 0; q < 4; ++q) {
            acc[c * 8 + q * 2]     += __uint_as_float(w[q] << 16);
            acc[c * 8 + q * 2 + 1] += __uint_as_float(w[q] & 0xffff0000u);
        }
    }
}

template<int MODE>
__device__ __forceinline__ void edge_body(const ushort* __restrict__ zb,
                                          const int* __restrict__ ia,
                                          const int* __restrict__ ib,
                                          const float* __restrict__ b1,
                                          const float* __restrict__ W2,
                                          const float* __restrict__ b2,
                                          float* __restrict__ o0p,
                                          float* __restrict__ o1p, int row)
{
    const uint4* p0;
    const uint4* p1;
    const uint4* p2 = nullptr;
    if constexpr (MODE == 1) {
        int2 p = ((const int2*)ia)[row];
        p0 = (const uint4*)(zb + (size_t)p.x * 32);
        p1 = (const uint4*)(zb + (size_t)p.y * 32);
    } else if constexpr (MODE == 2) {
        int c  = ia[row];
        int2 s = ((const int2*)ib)[row];
        p0 = (const uint4*)(zb + (size_t)c   * 32);
        p1 = (const uint4*)(zb + (size_t)s.x * 32);
        p2 = (const uint4*)(zb + (size_t)s.y * 32);
    } else {
        int4 q = ((const int4*)ia)[row];
        p0 = (const uint4*)(zb + (size_t)q.z * 32);
        p1 = (const uint4*)(zb + (size_t)q.w * 32);
    }

    float acc[32];
    #pragma unroll
    for (int j = 0; j < 32; ++j) acc[j] = b1[j];
    add_row_bf(acc, p0);
    add_row_bf(acc, p1);
    if constexpr (MODE == 2) add_row_bf(acc, p2);

    float o0 = b2[0], o1 = b2[1];
    #pragma unroll
    for (int j = 0; j < 32; ++j) {
        float t = fast_tanh(acc[j]);
        o0 = fmaf(t, W2[2 * j],     o0);
        o1 = fmaf(t, W2[2 * j + 1], o1);
    }
    o0p[row] = fabsf(o0);
    o1p[row] = fabsf(o1);
}

__device__ __forceinline__ void pair_body(const float2* __restrict__ ke,
                                          const int* __restrict__ idx,
                                          float* __restrict__ sig,
                                          float* __restrict__ eps,
                                          int i, int npair)
{
    if (i >= npair) return;
    int4 q = ((const int4*)idx)[i >> 1];
    float2 a0 = ke[q.x], b0 = ke[q.y];
    float2 a1 = ke[q.z], b1v = ke[q.w];
    sig[i]     = 0.5f * (a0.x + b0.x);
    eps[i]     = sqrtf(a0.y * b0.y);
    sig[i + 1] = 0.5f * (a1.x + b1v.x);
    eps[i + 1] = sqrtf(a1.y * b1v.y);
}

// All edge MLPs + both pair readouts in ONE dispatch (block-uniform routing).
__global__ __launch_bounds__(256)
void tail_k(const ushort* __restrict__ zb, const float2* __restrict__ ke,
            const int* __restrict__ bond, const int* __restrict__ angc,
            const int* __restrict__ angs, const int* __restrict__ tor,
            const int* __restrict__ i14, const int* __restrict__ inb,
            const float* __restrict__ b1, const float* __restrict__ W2,
            const float* __restrict__ b2, float* __restrict__ out)
{
    int bid = blockIdx.x;
    int tid = threadIdx.x;
    if (bid < NB_TOR) {
        int row = bid * 256 + tid;
        if (row < NTORSION)
            edge_body<3>(zb, tor, nullptr, b1, W2, b2,
                         out + OFF_TOR0, out + OFF_TOR1, row);
    } else if (bid < NB_TOR + NB_ANG) {
        int row = (bid - NB_TOR) * 256 + tid;
        if (row < NANGLE)
            edge_body<2>(zb, angc, angs, b1, W2, b2,
                         out + OFF_ANG0, out + OFF_ANG1, row);
    } else if (bid < NB_TOR + NB_ANG + NB_BOND) {
        int row = (bid - NB_TOR - NB_ANG) * 256 + tid;
        if (row < NBOND)
            edge_body<1>(zb, bond, nullptr, b1, W2, b2,
                         out + OFF_BOND0, out + OFF_BOND1, row);
    } else if (bid < NB_TOR + NB_ANG + NB_BOND + NB_14) {
        int i = ((bid - NB_TOR - NB_ANG - NB_BOND) * 256 + tid) * 2;
        pair_body(ke, i14, out + OFF_S14, out + OFF_E14, i, N14);
    } else {
        int i = ((bid - NB_TOR - NB_ANG - NB_BOND - NB_14) * 256 + tid) * 2;
        pair_body(ke, inb, out + OFF_SNB, out + OFF_ENB, i, NNB);
    }
}

// ---------------- fallback path (v1, known-good) ----------------

template<int MODE>
__global__ __launch_bounds__(256)
void mlp_k(const float* __restrict__ h,
           const int* __restrict__ ia, const int* __restrict__ ib,
           const float* __restrict__ W1, const float* __restrict__ b1,
           const float* __restrict__ W2, const float* __restrict__ b2,
           float* __restrict__ o0p, float* __restrict__ o1p, int n)
{
    __shared__ float sW1[128 * 32];
    __shared__ float sB1[32];
    __shared__ float sW2[64];
    __shared__ float sB2[2];

    const int tid = threadIdx.x;
    {
        const float4* W1v = (const float4*)W1;
        float4* sW1v = (float4*)sW1;
        #pragma unroll
        for (int i = 0; i < 4; ++i) sW1v[tid + 256 * i] = W1v[tid + 256 * i];
        if (tid < 32) sB1[tid] = b1[tid];
        if (tid < 64) sW2[tid] = W2[tid];
        if (tid < 2)  sB2[tid] = b2[tid];
    }
    __syncthreads();

    const int row = blockIdx.x * 256 + tid;
    if (row >= n) return;

    const float4* x0;
    const float4* x1 = nullptr;
    const float4* x2 = nullptr;
    if constexpr (MODE == 0) {
        x0 = (const float4*)(h + (size_t)row * 128);
    } else if constexpr (MODE == 1) {
        int2 p = ((const int2*)ia)[row];
        x0 = (const float4*)(h + (size_t)p.x * 128);
        x1 = (const float4*)(h + (size_t)p.y * 128);
    } else if constexpr (MODE == 2) {
        int c  = ia[row];
        int2 p = ((const int2*)ib)[row];
        x0 = (const float4*)(h + (size_t)c * 128);
        x1 = (const float4*)(h + (size_t)p.x * 128);
        x2 = (const float4*)(h + (size_t)p.y * 128);
    } else {
        int4 q = ((const int4*)ia)[row];
        x0 = (const float4*)(h + (size_t)q.z * 128);
        x1 = (const float4*)(h + (size_t)q.w * 128);
    }

    float acc[32];
    #pragma unroll
    for (int j = 0; j < 32; ++j) acc[j] = sB1[j];

    #pragma unroll 2
    for (int kk = 0; kk < 32; ++kk) {
        float4 a = x0[kk];
        if constexpr (MODE == 1 || MODE == 3) {
            float4 bq = x1[kk];
            a.x += bq.x; a.y += bq.y; a.z += bq.z; a.w += bq.w;
        } else if constexpr (MODE == 2) {
            float4 bq = x1[kk];
            float4 cq = x2[kk];
            a.x += bq.x + cq.x; a.y += bq.y + cq.y;
            a.z += bq.z + cq.z; a.w += bq.w + cq.w;
        }
        const float* wr = &sW1[kk * 4 * 32];
        #pragma unroll
        for (int j = 0; j < 32; ++j) acc[j] = fmaf(a.x, wr[j], acc[j]);
        #pragma unroll
        for (int j = 0; j < 32; ++j) acc[j] = fmaf(a.y, wr[32 + j], acc[j]);
        #pragma unroll
        for (int j = 0; j < 32; ++j) acc[j] = fmaf(a.z, wr[64 + j], acc[j]);
        #pragma unroll
        for (int j = 0; j < 32; ++j) acc[j] = fmaf(a.w, wr[96 + j], acc[j]);
    }

    float o0 = sB2[0], o1 = sB2[1];
    #pragma unroll
    for (int j = 0; j < 32; ++j) {
        float t = fast_tanh(acc[j]);
        o0 = fmaf(t, sW2[2 * j], o0);
        o1 = fmaf(t, sW2[2 * j + 1], o1);
    }
    o0p[row] = fabsf(o0);
    o1p[row] = fabsf(o1);
}

__global__ __launch_bounds__(256)
void pair_k(const float* __restrict__ kat, const float* __restrict__ eat,
            const int* __restrict__ idx,
            float* __restrict__ sig, float* __restrict__ eps, int n)
{
    int i = blockIdx.x * 256 + threadIdx.x;
    if (i >= n) return;
    int2 p = ((const int2*)idx)[i];
    float ka = kat[p.x], kb = kat[p.y];
    float ea = eat[p.x], eb = eat[p.y];
    sig[i] = 0.5f * (ka + kb);
    eps[i] = sqrtf(ea * eb);
}

extern "C" void kernel_launch(void* const* d_in, const int* in_sizes, int n_in,
                              void* d_out, int out_size, void* d_ws, size_t ws_size,
                              hipStream_t stream)
{
    const float* h     = (const float*)d_in[0];
    const int*   bond  = (const int*)d_in[1];
    const int*   ang_c = (const int*)d_in[2];
    const int*   ang_s = (const int*)d_in[3];
    const int*   tor   = (const int*)d_in[4];
    const int*   i14   = (const int*)d_in[5];
    const int*   inb   = (const int*)d_in[6];
    const float* W1a   = (const float*)d_in[7];
    const float* b1a   = (const float*)d_in[8];
    const float* W2a   = (const float*)d_in[9];
    const float* b2a   = (const float*)d_in[10];
    const float* W1b   = (const float*)d_in[11];
    const float* b1b   = (const float*)d_in[12];
    const float* W2b   = (const float*)d_in[13];
    const float* b2b   = (const float*)d_in[14];
    float* out = (float*)d_out;

    dim3 B(256);

    if (ws_size >= WS_NEED) {
        ushort* fragS = (ushort*)d_ws;
        const bf16x8* fragV = (const bf16x8*)d_ws;
        ushort* zb = (ushort*)((char*)d_ws + FRAG_BYTES);
        float2* ke = (float2*)((char*)d_ws + KE_OFF);

        build_frags_k<<<4, B, 0, stream>>>(W1a, W1b, fragS);

        atom_mfma_k<<<(NTILE + 3) / 4, B, 0, stream>>>(
            h, fragV, b1a, W2a, b2a,
            out + OFF_KATOM, out + OFF_EQATOM, zb, ke);

        tail_k<<<NB_TAIL, B, 0, stream>>>(
            zb, ke, bond, ang_c, ang_s, tor, i14, inb,
            b1b, W2b, b2b, out);
    } else {
        mlp_k<0><<<(NATOM    + 255) / 256, B, 0, stream>>>(h, nullptr, nullptr, W1a, b1a, W2a, b2a,
                                                           out + OFF_KATOM, out + OFF_EQATOM, NATOM);
        mlp_k<1><<<(NBOND    + 255) / 256, B, 0, stream>>>(h, bond, nullptr, W1b, b1b, W2b, b2b,
                                                           out + OFF_BOND0, out + OFF_BOND1, NBOND);
        mlp_k<2><<<(NANGLE   + 255) / 256, B, 0, stream>>>(h, ang_c, ang_s, W1b, b1b, W2b, b2b,
                                                           out + OFF_ANG0, out + OFF_ANG1, NANGLE);
        mlp_k<3><<<(NTORSION + 255) / 256, B, 0, stream>>>(h, tor, nullptr, W1b, b1b, W2b, b2b,
                                                           out + OFF_TOR0, out + OFF_TOR1, NTORSION);
        pair_k<<<(N14 + 255) / 256, B, 0, stream>>>(out + OFF_KATOM, out + OFF_EQATOM, i14,
                                                    out + OFF_S14, out + OFF_E14, N14);
        pair_k<<<(NNB + 255) / 256, B, 0, stream>>>(out + OFF_KATOM, out + OFF_EQATOM, inb,
                                                    out + OFF_SNB, out + OFF_ENB, NNB);
    }
}